// Round 1
// baseline (45.070 us; speedup 1.0000x reference)
//
#include <hip/hip_runtime.h>

#define MEMN 262144
#define DIM 128
#define BS 256
#define NPOS 8
#define NNEG 1024
#define KTOT (1 + NPOS + NNEG)              /* 1033 */
#define NCHUNK 8
#define CHUNKK ((KTOT + NCHUNK - 1) / NCHUNK) /* 130 */

__global__ __launch_bounds__(256) void avid_sim_kernel(
    const float* __restrict__ video, const float* __restrict__ audio,
    const float* __restrict__ view1, const float* __restrict__ view2,
    const int* __restrict__ y, const int* __restrict__ pos,
    const int* __restrict__ neg, float* __restrict__ out)
{
    const int bid   = blockIdx.x;
    const int m     = bid / (BS * NCHUNK);          // 0: v2a (query=video, mem=view2); 1: a2v
    const int rem   = bid - m * (BS * NCHUNK);
    const int b     = rem / NCHUNK;
    const int chunk = rem - b * NCHUNK;

    const float* q_src = (m == 0) ? (video + b * DIM) : (audio + b * DIM);
    const float* mem   = (m == 0) ? view2 : view1;

    const int g   = threadIdx.x & 15;   // lane within 16-lane group
    const int grp = threadIdx.x >> 4;   // 16 groups per block

    // Load this lane's 8-float query fragment (group collectively holds all 128)
    float4 q0 = *(const float4*)(q_src + g * 8);
    float4 q1 = *(const float4*)(q_src + g * 8 + 4);

    // Fused L2 normalization: group-reduce sum of squares
    float qq = q0.x*q0.x + q0.y*q0.y + q0.z*q0.z + q0.w*q0.w
             + q1.x*q1.x + q1.y*q1.y + q1.z*q1.z + q1.w*q1.w;
    qq += __shfl_xor(qq, 1);
    qq += __shfl_xor(qq, 2);
    qq += __shfl_xor(qq, 4);
    qq += __shfl_xor(qq, 8);
    const float scale = (1.0f / 0.07f) / fmaxf(sqrtf(qq), 1e-12f);
    q0.x *= scale; q0.y *= scale; q0.z *= scale; q0.w *= scale;
    q1.x *= scale; q1.y *= scale; q1.z *= scale; q1.w *= scale;

    float* outm = out + (size_t)m * BS * KTOT + (size_t)b * KTOT;

    const int k0 = chunk * CHUNKK;
    const int k1 = (k0 + CHUNKK < KTOT) ? (k0 + CHUNKK) : KTOT;

    for (int k = k0 + grp; k < k1; k += 16) {
        int idx;
        if (k == 0)          idx = y[b];
        else if (k <= NPOS)  idx = pos[b * NPOS + (k - 1)];
        else                 idx = neg[b * NNEG + (k - 1 - NPOS)];

        const float* row = mem + (size_t)idx * DIM;
        float4 r0 = *(const float4*)(row + g * 8);
        float4 r1 = *(const float4*)(row + g * 8 + 4);

        float s = q0.x*r0.x + q0.y*r0.y + q0.z*r0.z + q0.w*r0.w
                + q1.x*r1.x + q1.y*r1.y + q1.z*r1.z + q1.w*r1.w;
        s += __shfl_xor(s, 1);
        s += __shfl_xor(s, 2);
        s += __shfl_xor(s, 4);
        s += __shfl_xor(s, 8);
        if (g == 0) outm[k] = s;
    }
}

extern "C" void kernel_launch(void* const* d_in, const int* in_sizes, int n_in,
                              void* d_out, int out_size, void* d_ws, size_t ws_size,
                              hipStream_t stream) {
    const float* video = (const float*)d_in[0];
    const float* audio = (const float*)d_in[1];
    const float* view1 = (const float*)d_in[2];
    const float* view2 = (const float*)d_in[3];
    const int*   y     = (const int*)d_in[4];
    const int*   pos   = (const int*)d_in[5];
    const int*   neg   = (const int*)d_in[6];
    float* out = (float*)d_out;

    dim3 grid(2 * BS * NCHUNK);
    dim3 block(256);
    avid_sim_kernel<<<grid, block, 0, stream>>>(video, audio, view1, view2,
                                                y, pos, neg, out);
}

// Round 2
// 44.501 us; speedup vs baseline: 1.0128x; 1.0128x over previous
//
#include <hip/hip_runtime.h>

#define MEMN 262144
#define DIM 128
#define BS 256
#define NPOS 8
#define NNEG 1024
#define KTOT (1 + NPOS + NNEG)                 /* 1033 */
#define NCHUNK 8
#define CHUNKK ((KTOT + NCHUNK - 1) / NCHUNK)  /* 130 */
#define R 8                                    /* rows in flight per 16-lane group */

__global__ __launch_bounds__(256) void avid_sim_kernel(
    const float* __restrict__ video, const float* __restrict__ audio,
    const float* __restrict__ view1, const float* __restrict__ view2,
    const int* __restrict__ y, const int* __restrict__ pos,
    const int* __restrict__ neg, float* __restrict__ out)
{
    const int bid   = blockIdx.x;
    const int m     = bid / (BS * NCHUNK);      // 0: v2a (q=video, mem=view2); 1: a2v
    const int rem   = bid - m * (BS * NCHUNK);
    const int b     = rem / NCHUNK;
    const int chunk = rem - b * NCHUNK;

    const float* q_src = (m == 0) ? (video + b * DIM) : (audio + b * DIM);
    const float* mem   = (m == 0) ? view2 : view1;

    const int k0  = chunk * CHUNKK;
    const int cnt = (KTOT - k0 < CHUNKK) ? (KTOT - k0) : CHUNKK;

    // ---- stage this chunk's indices into LDS (one coalesced pass) ----
    __shared__ int s_idx[CHUNKK];
    if ((int)threadIdx.x < cnt) {
        const int k = k0 + (int)threadIdx.x;
        int idx;
        if (k == 0)          idx = y[b];
        else if (k <= NPOS)  idx = pos[b * NPOS + (k - 1)];
        else                 idx = neg[b * NNEG + (k - 1 - NPOS)];
        s_idx[threadIdx.x] = idx;
    }

    const int g   = threadIdx.x & 15;   // lane within 16-lane group
    const int grp = threadIdx.x >> 4;   // 16 groups

    // ---- query fragment + fused L2 normalization ----
    float4 q0 = *(const float4*)(q_src + g * 8);
    float4 q1 = *(const float4*)(q_src + g * 8 + 4);
    float qq = q0.x*q0.x + q0.y*q0.y + q0.z*q0.z + q0.w*q0.w
             + q1.x*q1.x + q1.y*q1.y + q1.z*q1.z + q1.w*q1.w;
    qq += __shfl_xor(qq, 1);
    qq += __shfl_xor(qq, 2);
    qq += __shfl_xor(qq, 4);
    qq += __shfl_xor(qq, 8);
    const float scale = (1.0f / 0.07f) / fmaxf(sqrtf(qq), 1e-12f);
    q0.x *= scale; q0.y *= scale; q0.z *= scale; q0.w *= scale;
    q1.x *= scale; q1.y *= scale; q1.z *= scale; q1.w *= scale;

    __syncthreads();

    float* outm = out + (size_t)m * BS * KTOT + (size_t)b * KTOT + k0;

    // ---- main: R rows per group in flight ----
    int kloc[R];
    const float* rowp[R];
#pragma unroll
    for (int i = 0; i < R; ++i) {
        int k = grp + i * 16;
        kloc[i] = k;
        int kc = (k < cnt) ? k : (cnt - 1);     // clamp: harmless dup load, no store
        rowp[i] = mem + (size_t)s_idx[kc] * DIM + g * 8;
    }
    float4 r0[R], r1[R];
#pragma unroll
    for (int i = 0; i < R; ++i) {               // 2R independent 16B loads in flight
        r0[i] = *(const float4*)(rowp[i]);
        r1[i] = *(const float4*)(rowp[i] + 4);
    }
#pragma unroll
    for (int i = 0; i < R; ++i) {
        float s = q0.x*r0[i].x + q0.y*r0[i].y + q0.z*r0[i].z + q0.w*r0[i].w
                + q1.x*r1[i].x + q1.y*r1[i].y + q1.z*r1[i].z + q1.w*r1[i].w;
        s += __shfl_xor(s, 1);
        s += __shfl_xor(s, 2);
        s += __shfl_xor(s, 4);
        s += __shfl_xor(s, 8);
        if (g == 0 && kloc[i] < cnt) outm[kloc[i]] = s;
    }
    // remainder rows (only when cnt > R*16, i.e. cnt=130 -> groups 0,1)
    for (int k = grp + R * 16; k < cnt; k += 16) {
        const float* row = mem + (size_t)s_idx[k] * DIM + g * 8;
        float4 a0 = *(const float4*)(row);
        float4 a1 = *(const float4*)(row + 4);
        float s = q0.x*a0.x + q0.y*a0.y + q0.z*a0.z + q0.w*a0.w
                + q1.x*a1.x + q1.y*a1.y + q1.z*a1.z + q1.w*a1.w;
        s += __shfl_xor(s, 1);
        s += __shfl_xor(s, 2);
        s += __shfl_xor(s, 4);
        s += __shfl_xor(s, 8);
        if (g == 0) outm[k] = s;
    }
}

extern "C" void kernel_launch(void* const* d_in, const int* in_sizes, int n_in,
                              void* d_out, int out_size, void* d_ws, size_t ws_size,
                              hipStream_t stream) {
    const float* video = (const float*)d_in[0];
    const float* audio = (const float*)d_in[1];
    const float* view1 = (const float*)d_in[2];
    const float* view2 = (const float*)d_in[3];
    const int*   y     = (const int*)d_in[4];
    const int*   pos   = (const int*)d_in[5];
    const int*   neg   = (const int*)d_in[6];
    float* out = (float*)d_out;

    dim3 grid(2 * BS * NCHUNK);
    dim3 block(256);
    avid_sim_kernel<<<grid, block, 0, stream>>>(video, audio, view1, view2,
                                                y, pos, neg, out);
}